// Round 6
// baseline (651.308 us; speedup 1.0000x reference)
//
#include <hip/hip_runtime.h>
#include <hip/hip_bf16.h>

#define N_TOK 262144
#define D_FEAT 128
#define C_CLS 64
#define TILE_M 128
#define DIST_BLOCKS 1024
#define SEG_BLOCKS 256
#define GRID_B (DIST_BLOCKS + SEG_BLOCKS)       // 1280
#define BLOCK_T 256
#define NTILES (N_TOK / TILE_M)                 // 2048
#define TILES_PER_BLOCK (NTILES / DIST_BLOCKS)  // 2
#define NSTEP (TILES_PER_BLOCK * 2)             // 4 (16-row steps per wave)
#define SEG_ELEMS (C_CLS * D_FEAT)              // 8192
#define SEG_ROWS (N_TOK / SEG_BLOCKS)           // 1024 rows per seg block
#define RED_BLOCKS 256
#define BCHUNK (SEG_BLOCKS / 8)                 // 32 slices per red-chunk

typedef __attribute__((ext_vector_type(8))) short bf16x8;
typedef __attribute__((ext_vector_type(4))) float f32x4;

__device__ __forceinline__ short f2bf(float x) {
    return (short)__bfloat16_as_ushort(__float2bfloat16(x));   // RTNE
}

__device__ __forceinline__ bf16x8 pack8(float4 a, float4 b) {
    bf16x8 t;
    t[0] = f2bf(a.x); t[1] = f2bf(a.y); t[2] = f2bf(a.z); t[3] = f2bf(a.w);
    t[4] = f2bf(b.x); t[5] = f2bf(b.y); t[6] = f2bf(b.z); t[7] = f2bf(b.w);
    return t;
}

__device__ __forceinline__ void gload_lds16(const float* g, float* l) {
    __builtin_amdgcn_global_load_lds(
        (const __attribute__((address_space(1))) void*)g,
        (__attribute__((address_space(3))) void*)l, 16, 0, 0);
}

// 8 global_load_lds (16B) staging rows [rbase..rbase+15] x 128 floats into
// buf[16][128]. LDS dest linear (HW: base + lane*16); the 16B-chunk XOR
// swizzle (chunk ^= row&7) rides on the GLOBAL source address (rule #21).
__device__ __forceinline__ void stage_issue(const float* __restrict__ f,
                                            int rbase, float* buf, int lane) {
    const int rl = lane >> 5;          // row within pair
    const int dc = lane & 31;          // dest chunk
    #pragma unroll
    for (int i = 0; i < 8; ++i) {
        const int r  = i * 2 + rl;
        const int sc = dc ^ (r & 7);   // swizzled source chunk
        gload_lds16(f + (size_t)(rbase + r) * D_FEAT + sc * 4,
                    buf + (i * 2) * D_FEAT);
    }
}

// v7: UNFUSE. One launch, two block roles running concurrently:
//   dist role (4 of 5 blocks): staging + MFMA + dist stores + loss. No seg
//     atomics. Counted vmcnt(16) so dist stores never gate the load wait.
//   seg role (1 of 5 blocks): pure streaming scatter-reduce into LDS seg,
//     slice flush. Reads f second -> mostly L2/L3 hits.
template<int MODE>
__global__ __launch_bounds__(BLOCK_T, 4) void center_main(
    const float* __restrict__ f, const int* __restrict__ label,
    const float* __restrict__ centers, float* __restrict__ dist_out,
    float* __restrict__ ws_loss, unsigned* __restrict__ ws_cnt,
    float* __restrict__ ws_seg, float* __restrict__ ws_part,
    unsigned* __restrict__ ws_pcnt, float* __restrict__ ws_ploss)
{
    __shared__ float    smem[SEG_ELEMS];   // dist: stage[4][16][128]; seg: seg sums
    __shared__ int      lseg[SEG_ROWS];    // seg role: 1024 labels
    __shared__ float    c2s[C_CLS];
    __shared__ float    f2t[TILE_M];
    __shared__ int      lblt[TILES_PER_BLOCK][TILE_M];
    __shared__ unsigned cnts[C_CLS];
    __shared__ float    wred[4];

    const int bid = blockIdx.x;
    const int tid = threadIdx.x;

    if ((bid % 5) == 4) {
        // ================= SEG ROLE =================
        const int si = bid / 5;                 // 0..255
        const int rb = si * SEG_ROWS;
        for (int i = tid; i < SEG_ELEMS; i += BLOCK_T) smem[i] = 0.f;
        if (tid < C_CLS) cnts[tid] = 0u;
        __syncthreads();
        for (int i = tid; i < SEG_ROWS; i += BLOCK_T) {
            const int lv = label[rb + i];
            lseg[i] = lv;
            atomicAdd(&cnts[lv], 1u);
        }
        __syncthreads();
        const int rof = tid >> 5;               // 0..7: 8 rows per iteration
        const int c4  = (tid & 31) << 2;        // float column (x4)
        #pragma unroll 4
        for (int it = 0; it < SEG_ROWS / 8; ++it) {
            const int rl = it * 8 + rof;
            const float4 vv = *(const float4*)(f + (size_t)(rb + rl) * D_FEAT + c4);
            float* sp = &smem[(lseg[rl] << 7) + c4];   // half-wave shares label
            atomicAdd(sp + 0, vv.x);
            atomicAdd(sp + 1, vv.y);
            atomicAdd(sp + 2, vv.z);
            atomicAdd(sp + 3, vv.w);
        }
        __syncthreads();
        if (MODE == 1) {
            float* dst = ws_part + (size_t)si * SEG_ELEMS;
            for (int i0 = tid * 4; i0 < SEG_ELEMS; i0 += BLOCK_T * 4)
                *(float4*)(dst + i0) = *(const float4*)(smem + i0);
            if (tid < C_CLS) ws_pcnt[si * C_CLS + tid] = cnts[tid];
        } else {
            for (int i = tid; i < SEG_ELEMS; i += BLOCK_T)
                unsafeAtomicAdd(&ws_seg[i], smem[i]);
            if (tid < C_CLS) atomicAdd(&ws_cnt[tid], cnts[tid]);
        }
        return;
    }

    // ================= DIST ROLE =================
    const int di   = (bid / 5) * 4 + (bid % 5);   // 0..1023
    const int lane = tid & 63;
    const int w    = tid >> 6;        // wave id 0..3
    const int qk   = lane >> 4;       // k-quad 0..3
    const int ln   = lane & 15;

    float* buf = smem + w * (16 * D_FEAT);   // this wave's 8KB staging buffer

    // issue stage for step 0 immediately (completes under setup)
    stage_issue(f, di * TILE_M + w * 32, buf, lane);

    // labels for both tiles (lanes 0-31 tile0, 32-63 tile1), held in reg
    const int tt = lane >> 5;
    const int lr = lane & 31;
    const int lv = label[(di + tt * DIST_BLOCKS) * TILE_M + w * 32 + lr];

    if (tid < C_CLS) {
        float s = 0.f;
        const float* cp = centers + tid * D_FEAT;
        for (int k = 0; k < D_FEAT; k += 4) {
            float4 c4 = *(const float4*)(cp + k);
            s += c4.x*c4.x + c4.y*c4.y + c4.z*c4.z + c4.w*c4.w;
        }
        c2s[tid] = s;
    }

    // B fragments (centers as bf16), registers for the whole kernel
    bf16x8 bfr[4][4];
    #pragma unroll
    for (int ct = 0; ct < 4; ++ct) {
        const float* bp = centers + (ct * 16 + ln) * D_FEAT + qk * 8;
        #pragma unroll
        for (int ks = 0; ks < 4; ++ks) {
            float4 v0 = *(const float4*)(bp + ks * 32);
            float4 v1 = *(const float4*)(bp + ks * 32 + 4);
            bfr[ct][ks] = pack8(v0, v1);
        }
    }
    __syncthreads();   // c2s ready
    lblt[tt][w * 32 + lr] = lv;

    float lossa = 0.f;

    for (int t = 0; t < NSTEP; ++t) {
        const int tl    = t >> 1;
        const int half  = t & 1;
        const int rbase = (di + tl * DIST_BLOCKS) * TILE_M + w * 32 + half * 16;

        // wait for this step's staged tile. t>0: 8 loads then 16 stores are
        // outstanding; FIFO retirement => vmcnt(16) proves the loads done
        // WITHOUT draining the dist stores (never vmcnt(0) in steady state).
        if (t == 0) asm volatile("s_waitcnt vmcnt(0)" ::: "memory");
        else        asm volatile("s_waitcnt vmcnt(16)" ::: "memory");
        __builtin_amdgcn_sched_barrier(0);

        // LDS -> regs: lane (qk,ln) = row ln, chunks (ks*8+qk*2+h) ^ (ln&7)
        float4 v[8];
        #pragma unroll
        for (int ks = 0; ks < 4; ++ks) {
            const int g0 = ks * 8 + qk * 2;
            v[2*ks]   = *(const float4*)(buf + ln * D_FEAT + ((g0    ) ^ (ln & 7)) * 4);
            v[2*ks+1] = *(const float4*)(buf + ln * D_FEAT + ((g0 + 1) ^ (ln & 7)) * 4);
        }

        // reads done -> safe to overwrite buffer with next stage
        asm volatile("s_waitcnt lgkmcnt(0)" ::: "memory");
        __builtin_amdgcn_sched_barrier(0);
        if (t + 1 < NSTEP) {
            const int t1 = t + 1;
            stage_issue(f, (di + (t1 >> 1) * DIST_BLOCKS) * TILE_M
                           + w * 32 + (t1 & 1) * 16, buf, lane);
        }

        // f2 from registers
        float s2 = 0.f;
        #pragma unroll
        for (int i = 0; i < 8; ++i)
            s2 += v[i].x*v[i].x + v[i].y*v[i].y + v[i].z*v[i].z + v[i].w*v[i].w;
        s2 += __shfl_xor(s2, 16);
        s2 += __shfl_xor(s2, 32);
        if (lane < 16) f2t[w * 32 + half * 16 + lane] = s2;

        // A fragments
        bf16x8 afr[4];
        #pragma unroll
        for (int ks = 0; ks < 4; ++ks) afr[ks] = pack8(v[2*ks], v[2*ks+1]);

        // MFMA + epilogue (16 scattered dword stores)
        const int mloc = w * 32 + half * 16 + qk * 4;
        #pragma unroll
        for (int ct = 0; ct < 4; ++ct) {
            f32x4 acc = {0.f, 0.f, 0.f, 0.f};
            #pragma unroll
            for (int ks = 0; ks < 4; ++ks)
                acc = __builtin_amdgcn_mfma_f32_16x16x32_bf16(
                    afr[ks], bfr[ct][ks], acc, 0, 0, 0);
            const int n    = ct * 16 + ln;
            const float cv = c2s[n];
            float* op = dist_out + (size_t)(rbase + qk * 4) * C_CLS + n;
            #pragma unroll
            for (int u = 0; u < 4; ++u) {
                const float dv = f2t[mloc + u] + cv - 2.f * acc[u];
                op[(size_t)u * C_CLS] = dv;
                if (lblt[tl][mloc + u] == n) lossa += dv;
            }
        }
    }

    // flush: loss only (counts live in the seg role)
    #pragma unroll
    for (int off = 32; off; off >>= 1) lossa += __shfl_xor(lossa, off);
    if (MODE == 1) {
        if (lane == 0) wred[w] = lossa;
        __syncthreads();
        if (tid == 0) ws_ploss[di] = wred[0] + wred[1] + wred[2] + wred[3];
    } else {
        if (lane == 0) unsafeAtomicAdd(ws_loss, lossa);
    }
}

// Reduce 256 seg slices -> ws_seg; counts; loss (1024 dist partials).
__global__ __launch_bounds__(256) void center_red(
    const float* __restrict__ ws_part, const unsigned* __restrict__ ws_pcnt,
    const float* __restrict__ ws_ploss, float* __restrict__ ws_seg,
    unsigned* __restrict__ ws_cnt, float* __restrict__ ws_loss)
{
    __shared__ float lred[4];
    const int tid = threadIdx.x;
    const int i   = (blockIdx.x & 31) * 256 + tid;      // 0..8191
    const int c0  = (blockIdx.x >> 5) * BCHUNK;         // slice range start
    float s = 0.f;
    #pragma unroll 8
    for (int b = 0; b < BCHUNK; ++b)
        s += ws_part[(size_t)(c0 + b) * SEG_ELEMS + i];
    unsafeAtomicAdd(&ws_seg[i], s);                     // 8 adds/addr, spread

    if ((blockIdx.x & 31) == 0 && tid < C_CLS) {        // 8 blocks handle counts
        unsigned cs = 0u;
        #pragma unroll 8
        for (int b = 0; b < BCHUNK; ++b)
            cs += ws_pcnt[(c0 + b) * C_CLS + tid];
        atomicAdd(&ws_cnt[tid], cs);
    }
    if (blockIdx.x == 0) {                              // loss: 1024 -> 1
        float ls = 0.f;
        #pragma unroll
        for (int k = tid; k < DIST_BLOCKS; k += 256) ls += ws_ploss[k];
        #pragma unroll
        for (int off = 32; off; off >>= 1) ls += __shfl_xor(ls, off);
        if ((tid & 63) == 0) lred[tid >> 6] = ls;
        __syncthreads();
        if (tid == 0) ws_loss[0] = lred[0] + lred[1] + lred[2] + lred[3];
    }
}

__global__ void center_fin(const float* __restrict__ centers,
                           const float* __restrict__ ws_loss,
                           const unsigned* __restrict__ ws_cnt,
                           const float* __restrict__ ws_seg,
                           float* __restrict__ out)
{
    const int i = blockIdx.x * 256 + threadIdx.x;
    if (i == 0) out[0] = ws_loss[0] / ((float)N_TOK * (float)D_FEAT);
    if (i < SEG_ELEMS) {
        const int c = i >> 7;
        const unsigned cnt = ws_cnt[c];
        const float denom = (float)(cnt > 1u ? cnt : 1u);
        out[1 + i] = ((float)cnt * centers[i] - ws_seg[i]) / denom;
    }
}

extern "C" void kernel_launch(void* const* d_in, const int* in_sizes, int n_in,
                              void* d_out, int out_size, void* d_ws, size_t ws_size,
                              hipStream_t stream)
{
    const float* f       = (const float*)d_in[0];
    const int*   lbl     = (const int*)d_in[1];
    const float* centers = (const float*)d_in[2];
    float* out = (float*)d_out;

    float*    ws_loss  = (float*)d_ws;
    unsigned* ws_cnt   = (unsigned*)((char*)d_ws + 256);
    float*    ws_seg   = (float*)((char*)d_ws + 1024);
    char*     p        = (char*)d_ws + 1024 + SEG_ELEMS * sizeof(float);
    float*    ws_part  = (float*)p;                                   // 8.39 MB
    unsigned* ws_pcnt  = (unsigned*)(p + (size_t)SEG_BLOCKS * SEG_ELEMS * sizeof(float));
    float*    ws_ploss = (float*)(p + (size_t)SEG_BLOCKS * SEG_ELEMS * sizeof(float)
                                     + (size_t)SEG_BLOCKS * C_CLS * sizeof(unsigned));

    const size_t need = 1024 + SEG_ELEMS * sizeof(float)
                      + (size_t)SEG_BLOCKS * SEG_ELEMS * sizeof(float)
                      + (size_t)SEG_BLOCKS * C_CLS * sizeof(unsigned)
                      + (size_t)DIST_BLOCKS * sizeof(float);

    // zero the small accumulators only (slices fully written before read)
    hipMemsetAsync(d_ws, 0, 1024 + SEG_ELEMS * sizeof(float), stream);

    float* dist_out = out + 1 + SEG_ELEMS;
    if (ws_size >= need) {
        center_main<1><<<GRID_B, BLOCK_T, 0, stream>>>(f, lbl, centers, dist_out,
            ws_loss, ws_cnt, ws_seg, ws_part, ws_pcnt, ws_ploss);
        center_red<<<RED_BLOCKS, 256, 0, stream>>>(ws_part, ws_pcnt, ws_ploss,
                                                   ws_seg, ws_cnt, ws_loss);
    } else {
        center_main<0><<<GRID_B, BLOCK_T, 0, stream>>>(f, lbl, centers, dist_out,
            ws_loss, ws_cnt, ws_seg, ws_part, ws_pcnt, ws_ploss);
    }
    center_fin<<<32, 256, 0, stream>>>(centers, ws_loss, ws_cnt, ws_seg, out);
}

// Round 7
// 366.465 us; speedup vs baseline: 1.7773x; 1.7773x over previous
//
#include <hip/hip_runtime.h>
#include <hip/hip_bf16.h>

#define N_TOK 262144
#define D_FEAT 128
#define C_CLS 64
#define TILE_M 128                      // rows per dist tile (4 waves x 32)
#define DIST_BLOCKS 1024
#define BLOCK_T 256
#define TILES_PER_BLOCK 2               // N_TOK / TILE_M / DIST_BLOCKS
#define NSTEP (TILES_PER_BLOCK * 2)     // 4 (16-row steps per wave)
#define SEG_ELEMS (C_CLS * D_FEAT)      // 8192
#define SEG_BLOCKS 1024
#define SEG_ROWS_B (N_TOK / SEG_BLOCKS) // 256 rows per seg block
#define SEG_KSTEPS (SEG_ROWS_B / 32)    // 8
#define RED_BLOCKS 256
#define BCHUNK (SEG_BLOCKS / 8)         // 128 slices per red chunk

typedef __attribute__((ext_vector_type(8))) short bf16x8;
typedef __attribute__((ext_vector_type(4))) float f32x4;

__device__ __forceinline__ short f2bf(float x) {
    return (short)__bfloat16_as_ushort(__float2bfloat16(x));   // RTNE
}

__device__ __forceinline__ bf16x8 pack8(float4 a, float4 b) {
    bf16x8 t;
    t[0] = f2bf(a.x); t[1] = f2bf(a.y); t[2] = f2bf(a.z); t[3] = f2bf(a.w);
    t[4] = f2bf(b.x); t[5] = f2bf(b.y); t[6] = f2bf(b.z); t[7] = f2bf(b.w);
    return t;
}

__device__ __forceinline__ void gload_lds16(const float* g, float* l) {
    __builtin_amdgcn_global_load_lds(
        (const __attribute__((address_space(1))) void*)g,
        (__attribute__((address_space(3))) void*)l, 16, 0, 0);
}

// 8 global_load_lds (16B) staging rows [rbase..rbase+15] x 128 floats into
// buf[16][128]. LDS dest linear (HW: base + lane*16); the 16B-chunk XOR
// swizzle (chunk ^= row&7) rides on the GLOBAL source address (rule #21).
__device__ __forceinline__ void stage_issue(const float* __restrict__ f,
                                            int rbase, float* buf, int lane) {
    const int rl = lane >> 5;          // row within pair
    const int dc = lane & 31;          // dest chunk
    #pragma unroll
    for (int i = 0; i < 8; ++i) {
        const int r  = i * 2 + rl;
        const int sc = dc ^ (r & 7);   // swizzled source chunk
        gload_lds16(f + (size_t)(rbase + r) * D_FEAT + sc * 4,
                    buf + (i * 2) * D_FEAT);
    }
}

// v8a: dist-only kernel (R5 loop minus ALL seg/cnt work). LDS 35 KB ->
// 4 blocks/CU = 16 waves/CU (2x R5's MLP). Counted vmcnt(16): at each wait
// the 16 newest outstanding vmem ops are this wave's dist stores, so
// waiting-to-16 proves the 8 staged loads done WITHOUT draining stores.
template<int MODE>
__global__ __launch_bounds__(BLOCK_T, 4) void dist_main(
    const float* __restrict__ f, const int* __restrict__ label,
    const float* __restrict__ centers, float* __restrict__ dist_out,
    float* __restrict__ ws_loss, float* __restrict__ ws_ploss)
{
    __shared__ float stage4[4][16][D_FEAT];   // 32 KB: per-wave 8KB staging
    __shared__ float c2s[C_CLS];
    __shared__ float f2t[TILE_M];
    __shared__ int   lblt[TILES_PER_BLOCK][TILE_M];
    __shared__ float wred[4];

    const int tid  = threadIdx.x;
    const int lane = tid & 63;
    const int w    = tid >> 6;        // wave id 0..3
    const int qk   = lane >> 4;       // k-quad 0..3
    const int ln   = lane & 15;
    const int di   = blockIdx.x;

    float* buf = &stage4[w][0][0];

    // issue stage for step 0 immediately (completes under setup)
    stage_issue(f, di * TILE_M + w * 32, buf, lane);

    // labels for both tiles (lanes 0-31 tile0, 32-63 tile1)
    const int tt = lane >> 5;
    const int lr = lane & 31;
    const int lv = label[(di + tt * DIST_BLOCKS) * TILE_M + w * 32 + lr];

    if (tid < C_CLS) {
        float s = 0.f;
        const float* cp = centers + tid * D_FEAT;
        for (int k = 0; k < D_FEAT; k += 4) {
            float4 c4 = *(const float4*)(cp + k);
            s += c4.x*c4.x + c4.y*c4.y + c4.z*c4.z + c4.w*c4.w;
        }
        c2s[tid] = s;
    }

    // B fragments (centers as bf16), registers for the whole kernel
    bf16x8 bfr[4][4];
    #pragma unroll
    for (int ct = 0; ct < 4; ++ct) {
        const float* bp = centers + (ct * 16 + ln) * D_FEAT + qk * 8;
        #pragma unroll
        for (int ks = 0; ks < 4; ++ks) {
            float4 v0 = *(const float4*)(bp + ks * 32);
            float4 v1 = *(const float4*)(bp + ks * 32 + 4);
            bfr[ct][ks] = pack8(v0, v1);
        }
    }
    __syncthreads();   // c2s ready (also drains step-0 stage; acceptable once)
    lblt[tt][w * 32 + lr] = lv;

    float lossa = 0.f;

    for (int t = 0; t < NSTEP; ++t) {
        const int tl    = t >> 1;
        const int half  = t & 1;
        const int rbase = (di + tl * DIST_BLOCKS) * TILE_M + w * 32 + half * 16;

        if (t == 0) asm volatile("s_waitcnt vmcnt(0)" ::: "memory");
        else        asm volatile("s_waitcnt vmcnt(16)" ::: "memory");
        __builtin_amdgcn_sched_barrier(0);

        // LDS -> regs: lane (qk,ln) = row ln, chunks (ks*8+qk*2+h) ^ (ln&7)
        float4 v[8];
        #pragma unroll
        for (int ks = 0; ks < 4; ++ks) {
            const int g0 = ks * 8 + qk * 2;
            v[2*ks]   = *(const float4*)(buf + ln * D_FEAT + ((g0    ) ^ (ln & 7)) * 4);
            v[2*ks+1] = *(const float4*)(buf + ln * D_FEAT + ((g0 + 1) ^ (ln & 7)) * 4);
        }

        // reads done -> safe to overwrite buffer with next stage
        asm volatile("s_waitcnt lgkmcnt(0)" ::: "memory");
        __builtin_amdgcn_sched_barrier(0);
        if (t + 1 < NSTEP) {
            const int t1 = t + 1;
            stage_issue(f, (di + (t1 >> 1) * DIST_BLOCKS) * TILE_M
                           + w * 32 + (t1 & 1) * 16, buf, lane);
        }

        // f2 from registers
        float s2 = 0.f;
        #pragma unroll
        for (int i = 0; i < 8; ++i)
            s2 += v[i].x*v[i].x + v[i].y*v[i].y + v[i].z*v[i].z + v[i].w*v[i].w;
        s2 += __shfl_xor(s2, 16);
        s2 += __shfl_xor(s2, 32);
        if (lane < 16) f2t[w * 32 + half * 16 + lane] = s2;

        // A fragments
        bf16x8 afr[4];
        #pragma unroll
        for (int ks = 0; ks < 4; ++ks) afr[ks] = pack8(v[2*ks], v[2*ks+1]);

        // MFMA + epilogue (16 store-dwords per lane per step)
        const int mloc = w * 32 + half * 16 + qk * 4;
        #pragma unroll
        for (int ct = 0; ct < 4; ++ct) {
            f32x4 acc = {0.f, 0.f, 0.f, 0.f};
            #pragma unroll
            for (int ks = 0; ks < 4; ++ks)
                acc = __builtin_amdgcn_mfma_f32_16x16x32_bf16(
                    afr[ks], bfr[ct][ks], acc, 0, 0, 0);
            const int n    = ct * 16 + ln;
            const float cv = c2s[n];
            float* op = dist_out + (size_t)(rbase + qk * 4) * C_CLS + n;
            #pragma unroll
            for (int u = 0; u < 4; ++u) {
                const float dv = f2t[mloc + u] + cv - 2.f * acc[u];
                op[(size_t)u * C_CLS] = dv;
                if (lblt[tl][mloc + u] == n) lossa += dv;
            }
        }
    }

    // loss flush only
    #pragma unroll
    for (int off = 32; off; off >>= 1) lossa += __shfl_xor(lossa, off);
    if (MODE == 1) {
        if (lane == 0) wred[w] = lossa;
        __syncthreads();
        if (tid == 0) ws_ploss[di] = wred[0] + wred[1] + wred[2] + wred[3];
    } else {
        if (lane == 0) unsafeAtomicAdd(ws_loss, lossa);
    }
}

// v8b: segment sums via one-hot MFMA — zero atomics in the hot path.
// seg[c][d] = sum_rows onehot[row][c] * f[row][d]. A-frag = onehot built from
// 8 label compares (bf16 1.0 = 0x3F80, exact); B-frag = transposed dword
// loads of f (L3-hot: runs after dist_main). Per wave: 32 f32 accumulators.
template<int MODE>
__global__ __launch_bounds__(BLOCK_T, 4) void seg_main(
    const float* __restrict__ f, const int* __restrict__ label,
    float* __restrict__ ws_seg, unsigned* __restrict__ ws_cnt,
    float* __restrict__ ws_part, unsigned* __restrict__ ws_pcnt)
{
    __shared__ int      lblt[SEG_ROWS_B];
    __shared__ unsigned cnts[C_CLS];

    const int tid  = threadIdx.x;
    const int lane = tid & 63;
    const int w    = tid >> 6;        // wave id 0..3 -> d-cols [w*32, w*32+32)
    const int qk   = lane >> 4;
    const int ln   = lane & 15;
    const int sb   = blockIdx.x;
    const int r0   = sb * SEG_ROWS_B;

    if (tid < C_CLS) cnts[tid] = 0u;
    __syncthreads();
    {
        const int lv = label[r0 + tid];   // 256 rows, 256 threads
        lblt[tid] = lv;
        atomicAdd(&cnts[lv], 1u);         // 256 LDS atomics/block: negligible
    }
    __syncthreads();

    const int cbase = w * 32;
    f32x4 acc[4][2];                      // [c-tile][d-tile], 32 VGPR
    #pragma unroll
    for (int ct = 0; ct < 4; ++ct) {
        acc[ct][0] = (f32x4){0.f, 0.f, 0.f, 0.f};
        acc[ct][1] = (f32x4){0.f, 0.f, 0.f, 0.f};
    }

    for (int kk = 0; kk < SEG_KSTEPS; ++kk) {
        const int kr = kk * 32 + qk * 8;  // this lane's 8 k-rows
        // B-frags: b[dt][j] = f[r0+kr+j][cbase+dt*16+ln]  (k=row in reg dim)
        const float* bp = f + (size_t)(r0 + kr) * D_FEAT + cbase + ln;
        float b0[8], b1[8];
        #pragma unroll
        for (int j = 0; j < 8; ++j) {
            b0[j] = bp[(size_t)j * D_FEAT];
            b1[j] = bp[(size_t)j * D_FEAT + 16];
        }
        int lb[8];
        #pragma unroll
        for (int j = 0; j < 8; ++j) lb[j] = lblt[kr + j];   // LDS broadcast
        bf16x8 bf0, bf1;
        #pragma unroll
        for (int j = 0; j < 8; ++j) { bf0[j] = f2bf(b0[j]); bf1[j] = f2bf(b1[j]); }
        #pragma unroll
        for (int ct = 0; ct < 4; ++ct) {
            const int cls = ct * 16 + ln;   // A-frag: m = ln (class), k = qk*8+j
            bf16x8 a;
            #pragma unroll
            for (int j = 0; j < 8; ++j)
                a[j] = (lb[j] == cls) ? (short)0x3F80 : (short)0;
            acc[ct][0] = __builtin_amdgcn_mfma_f32_16x16x32_bf16(a, bf0, acc[ct][0], 0, 0, 0);
            acc[ct][1] = __builtin_amdgcn_mfma_f32_16x16x32_bf16(a, bf1, acc[ct][1], 0, 0, 0);
        }
    }

    // D layout: m(class) = qk*4+u, n(d) = ln  ->  seg[ct*16+qk*4+u][cbase+dt*16+ln]
    if (MODE == 1) {
        float* dst = ws_part + (size_t)sb * SEG_ELEMS;
        #pragma unroll
        for (int ct = 0; ct < 4; ++ct)
            #pragma unroll
            for (int dt = 0; dt < 2; ++dt)
                #pragma unroll
                for (int u = 0; u < 4; ++u)
                    dst[(ct * 16 + qk * 4 + u) * D_FEAT + cbase + dt * 16 + ln] = acc[ct][dt][u];
        if (tid < C_CLS) ws_pcnt[sb * C_CLS + tid] = cnts[tid];
    } else {
        #pragma unroll
        for (int ct = 0; ct < 4; ++ct)
            for (int dt = 0; dt < 2; ++dt)
                for (int u = 0; u < 4; ++u)
                    unsafeAtomicAdd(&ws_seg[(ct * 16 + qk * 4 + u) * D_FEAT
                                            + cbase + dt * 16 + ln], acc[ct][dt][u]);
        if (tid < C_CLS) atomicAdd(&ws_cnt[tid], cnts[tid]);
    }
}

// Reduce 1024 slices -> ws_seg (linear, no swizzle now); counts; loss.
__global__ __launch_bounds__(256) void center_red(
    const float* __restrict__ ws_part, const unsigned* __restrict__ ws_pcnt,
    const float* __restrict__ ws_ploss, float* __restrict__ ws_seg,
    unsigned* __restrict__ ws_cnt, float* __restrict__ ws_loss)
{
    __shared__ float lred[4];
    const int tid = threadIdx.x;
    const int i   = (blockIdx.x & 31) * 256 + tid;      // 0..8191
    const int c0  = (blockIdx.x >> 5) * BCHUNK;         // slice range start
    float s = 0.f;
    #pragma unroll 8
    for (int b = 0; b < BCHUNK; ++b)
        s += ws_part[(size_t)(c0 + b) * SEG_ELEMS + i];
    unsafeAtomicAdd(&ws_seg[i], s);                     // 8 adds/addr, spread

    if ((blockIdx.x & 31) == 0 && tid < C_CLS) {        // 8 blocks handle counts
        unsigned cs = 0u;
        #pragma unroll 8
        for (int b = 0; b < BCHUNK; ++b)
            cs += ws_pcnt[(c0 + b) * C_CLS + tid];
        atomicAdd(&ws_cnt[tid], cs);
    }
    if (blockIdx.x == 0) {                              // loss: 1024 -> 1
        float ls = 0.f;
        for (int k = tid; k < DIST_BLOCKS; k += 256) ls += ws_ploss[k];
        #pragma unroll
        for (int off = 32; off; off >>= 1) ls += __shfl_xor(ls, off);
        if ((tid & 63) == 0) lred[tid >> 6] = ls;
        __syncthreads();
        if (tid == 0) ws_loss[0] = lred[0] + lred[1] + lred[2] + lred[3];
    }
}

__global__ void center_fin(const float* __restrict__ centers,
                           const float* __restrict__ ws_loss,
                           const unsigned* __restrict__ ws_cnt,
                           const float* __restrict__ ws_seg,
                           float* __restrict__ out)
{
    const int i = blockIdx.x * 256 + threadIdx.x;
    if (i == 0) out[0] = ws_loss[0] / ((float)N_TOK * (float)D_FEAT);
    if (i < SEG_ELEMS) {
        const int c = i >> 7;
        const unsigned cnt = ws_cnt[c];
        const float denom = (float)(cnt > 1u ? cnt : 1u);
        out[1 + i] = ((float)cnt * centers[i] - ws_seg[i]) / denom;
    }
}

extern "C" void kernel_launch(void* const* d_in, const int* in_sizes, int n_in,
                              void* d_out, int out_size, void* d_ws, size_t ws_size,
                              hipStream_t stream)
{
    const float* f       = (const float*)d_in[0];
    const int*   lbl     = (const int*)d_in[1];
    const float* centers = (const float*)d_in[2];
    float* out = (float*)d_out;

    float*    ws_loss  = (float*)d_ws;
    unsigned* ws_cnt   = (unsigned*)((char*)d_ws + 256);
    float*    ws_seg   = (float*)((char*)d_ws + 1024);
    char*     p        = (char*)d_ws + 1024 + SEG_ELEMS * sizeof(float);
    float*    ws_part  = (float*)p;                                   // 33.55 MB
    unsigned* ws_pcnt  = (unsigned*)(p + (size_t)SEG_BLOCKS * SEG_ELEMS * sizeof(float));
    float*    ws_ploss = (float*)(p + (size_t)SEG_BLOCKS * SEG_ELEMS * sizeof(float)
                                     + (size_t)SEG_BLOCKS * C_CLS * sizeof(unsigned));

    const size_t need = 1024 + SEG_ELEMS * sizeof(float)
                      + (size_t)SEG_BLOCKS * SEG_ELEMS * sizeof(float)
                      + (size_t)SEG_BLOCKS * C_CLS * sizeof(unsigned)
                      + (size_t)DIST_BLOCKS * sizeof(float);

    // zero small accumulators only (slices fully written before read)
    hipMemsetAsync(d_ws, 0, 1024 + SEG_ELEMS * sizeof(float), stream);

    float* dist_out = out + 1 + SEG_ELEMS;
    if (ws_size >= need) {
        dist_main<1><<<DIST_BLOCKS, BLOCK_T, 0, stream>>>(f, lbl, centers, dist_out,
                                                          ws_loss, ws_ploss);
        seg_main<1><<<SEG_BLOCKS, BLOCK_T, 0, stream>>>(f, lbl, ws_seg, ws_cnt,
                                                        ws_part, ws_pcnt);
        center_red<<<RED_BLOCKS, 256, 0, stream>>>(ws_part, ws_pcnt, ws_ploss,
                                                   ws_seg, ws_cnt, ws_loss);
    } else {
        dist_main<0><<<DIST_BLOCKS, BLOCK_T, 0, stream>>>(f, lbl, centers, dist_out,
                                                          ws_loss, ws_ploss);
        seg_main<0><<<SEG_BLOCKS, BLOCK_T, 0, stream>>>(f, lbl, ws_seg, ws_cnt,
                                                        ws_part, ws_pcnt);
    }
    center_fin<<<32, 256, 0, stream>>>(centers, ws_loss, ws_cnt, ws_seg, out);
}

// Round 8
// 294.538 us; speedup vs baseline: 2.2113x; 1.2442x over previous
//
#include <hip/hip_runtime.h>
#include <hip/hip_bf16.h>

#define N_TOK 262144
#define D_FEAT 128
#define C_CLS 64
#define TILE_M 128                      // rows per dist tile (4 waves x 32)
#define DIST_BLOCKS 1024
#define BLOCK_T 256
#define TILES_PER_BLOCK 2               // N_TOK / TILE_M / DIST_BLOCKS
#define NSTEP (TILES_PER_BLOCK * 2)     // 4 (16-row steps per wave)
#define SEG_ELEMS (C_CLS * D_FEAT)      // 8192
#define SEG_BLOCKS 1024
#define SEG_ROWS_B (N_TOK / SEG_BLOCKS) // 256 rows per seg block
#define SEG_KSTEPS (SEG_ROWS_B / 32)    // 8

typedef __attribute__((ext_vector_type(8))) short bf16x8;
typedef __attribute__((ext_vector_type(4))) float f32x4;

__device__ __forceinline__ short f2bf(float x) {
    return (short)__bfloat16_as_ushort(__float2bfloat16(x));   // RTNE
}

__device__ __forceinline__ bf16x8 pack8(float4 a, float4 b) {
    bf16x8 t;
    t[0] = f2bf(a.x); t[1] = f2bf(a.y); t[2] = f2bf(a.z); t[3] = f2bf(a.w);
    t[4] = f2bf(b.x); t[5] = f2bf(b.y); t[6] = f2bf(b.z); t[7] = f2bf(b.w);
    return t;
}

__device__ __forceinline__ void gload_lds16(const float* g, float* l) {
    __builtin_amdgcn_global_load_lds(
        (const __attribute__((address_space(1))) void*)g,
        (__attribute__((address_space(3))) void*)l, 16, 0, 0);
}

// 8 global_load_lds (16B) staging rows [rbase..rbase+15] x 128 floats into
// buf[16][128]. LDS dest linear (HW: base + lane*16); the 16B-chunk XOR
// swizzle (chunk ^= row&7) rides on the GLOBAL source address (rule #21).
__device__ __forceinline__ void stage_issue(const float* __restrict__ f,
                                            int rbase, float* buf, int lane) {
    const int rl = lane >> 5;          // row within pair
    const int dc = lane & 31;          // dest chunk
    #pragma unroll
    for (int i = 0; i < 8; ++i) {
        const int r  = i * 2 + rl;
        const int sc = dc ^ (r & 7);   // swizzled source chunk
        gload_lds16(f + (size_t)(rbase + r) * D_FEAT + sc * 4,
                    buf + (i * 2) * D_FEAT);
    }
}

// v9a: dist-only. Identical hot loop to R7, but: launch_bounds(256,2)
// (R5's known-good regalloc regime — R7's (256,4) caused a 64-VGPR spill
// cliff, ~290MB scratch traffic), and NO template co-instantiation
// (rule #19): mode is a runtime arg used only in the epilogue.
__global__ __launch_bounds__(BLOCK_T, 2) void dist_main(
    const float* __restrict__ f, const int* __restrict__ label,
    const float* __restrict__ centers, float* __restrict__ dist_out,
    float* __restrict__ ws_loss, float* __restrict__ ws_ploss, int mode)
{
    __shared__ float stage4[4][16][D_FEAT];   // 32 KB: per-wave 8KB staging
    __shared__ float c2s[C_CLS];
    __shared__ float f2t[TILE_M];
    __shared__ int   lblt[TILES_PER_BLOCK][TILE_M];
    __shared__ float wred[4];

    const int tid  = threadIdx.x;
    const int lane = tid & 63;
    const int w    = tid >> 6;        // wave id 0..3
    const int qk   = lane >> 4;       // k-quad 0..3
    const int ln   = lane & 15;
    const int di   = blockIdx.x;

    float* buf = &stage4[w][0][0];

    // issue stage for step 0 immediately (completes under setup)
    stage_issue(f, di * TILE_M + w * 32, buf, lane);

    // labels for both tiles (lanes 0-31 tile0, 32-63 tile1)
    const int tt = lane >> 5;
    const int lr = lane & 31;
    const int lv = label[(di + tt * DIST_BLOCKS) * TILE_M + w * 32 + lr];

    if (tid < C_CLS) {
        float s = 0.f;
        const float* cp = centers + tid * D_FEAT;
        for (int k = 0; k < D_FEAT; k += 4) {
            float4 c4 = *(const float4*)(cp + k);
            s += c4.x*c4.x + c4.y*c4.y + c4.z*c4.z + c4.w*c4.w;
        }
        c2s[tid] = s;
    }

    // B fragments (centers as bf16), registers for the whole kernel
    bf16x8 bfr[4][4];
    #pragma unroll
    for (int ct = 0; ct < 4; ++ct) {
        const float* bp = centers + (ct * 16 + ln) * D_FEAT + qk * 8;
        #pragma unroll
        for (int ks = 0; ks < 4; ++ks) {
            float4 v0 = *(const float4*)(bp + ks * 32);
            float4 v1 = *(const float4*)(bp + ks * 32 + 4);
            bfr[ct][ks] = pack8(v0, v1);
        }
    }
    __syncthreads();   // c2s ready
    lblt[tt][w * 32 + lr] = lv;

    float lossa = 0.f;

    for (int t = 0; t < NSTEP; ++t) {
        const int tl    = t >> 1;
        const int half  = t & 1;
        const int rbase = (di + tl * DIST_BLOCKS) * TILE_M + w * 32 + half * 16;

        // Counted wait: at t>0 outstanding = 8 staged loads (oldest) + 16
        // dist stores (newest); FIFO => vmcnt(16) proves loads done without
        // ever draining stores in the loop.
        if (t == 0) asm volatile("s_waitcnt vmcnt(0)" ::: "memory");
        else        asm volatile("s_waitcnt vmcnt(16)" ::: "memory");
        __builtin_amdgcn_sched_barrier(0);

        // LDS -> regs: lane (qk,ln) = row ln, chunks (ks*8+qk*2+h) ^ (ln&7)
        float4 v[8];
        #pragma unroll
        for (int ks = 0; ks < 4; ++ks) {
            const int g0 = ks * 8 + qk * 2;
            v[2*ks]   = *(const float4*)(buf + ln * D_FEAT + ((g0    ) ^ (ln & 7)) * 4);
            v[2*ks+1] = *(const float4*)(buf + ln * D_FEAT + ((g0 + 1) ^ (ln & 7)) * 4);
        }

        // reads done -> safe to overwrite buffer with next stage
        asm volatile("s_waitcnt lgkmcnt(0)" ::: "memory");
        __builtin_amdgcn_sched_barrier(0);
        if (t + 1 < NSTEP) {
            const int t1 = t + 1;
            stage_issue(f, (di + (t1 >> 1) * DIST_BLOCKS) * TILE_M
                           + w * 32 + (t1 & 1) * 16, buf, lane);
        }

        // f2 from registers
        float s2 = 0.f;
        #pragma unroll
        for (int i = 0; i < 8; ++i)
            s2 += v[i].x*v[i].x + v[i].y*v[i].y + v[i].z*v[i].z + v[i].w*v[i].w;
        s2 += __shfl_xor(s2, 16);
        s2 += __shfl_xor(s2, 32);
        if (lane < 16) f2t[w * 32 + half * 16 + lane] = s2;

        // A fragments
        bf16x8 afr[4];
        #pragma unroll
        for (int ks = 0; ks < 4; ++ks) afr[ks] = pack8(v[2*ks], v[2*ks+1]);

        // MFMA + epilogue (16 store-dwords per lane per step)
        const int mloc = w * 32 + half * 16 + qk * 4;
        #pragma unroll
        for (int ct = 0; ct < 4; ++ct) {
            f32x4 acc = {0.f, 0.f, 0.f, 0.f};
            #pragma unroll
            for (int ks = 0; ks < 4; ++ks)
                acc = __builtin_amdgcn_mfma_f32_16x16x32_bf16(
                    afr[ks], bfr[ct][ks], acc, 0, 0, 0);
            const int n    = ct * 16 + ln;
            const float cv = c2s[n];
            float* op = dist_out + (size_t)(rbase + qk * 4) * C_CLS + n;
            #pragma unroll
            for (int u = 0; u < 4; ++u) {
                const float dv = f2t[mloc + u] + cv - 2.f * acc[u];
                op[(size_t)u * C_CLS] = dv;
                if (lblt[tl][mloc + u] == n) lossa += dv;
            }
        }
    }

    // loss flush only
    #pragma unroll
    for (int off = 32; off; off >>= 1) lossa += __shfl_xor(lossa, off);
    if (mode == 1) {
        if (lane == 0) wred[w] = lossa;
        __syncthreads();
        if (tid == 0) ws_ploss[di] = wred[0] + wred[1] + wred[2] + wred[3];
    } else {
        if (lane == 0) unsafeAtomicAdd(ws_loss, lossa);
    }
}

// v9b: segment sums via one-hot MFMA (R7 body, de-templated).
__global__ __launch_bounds__(BLOCK_T, 4) void seg_main(
    const float* __restrict__ f, const int* __restrict__ label,
    float* __restrict__ ws_seg, unsigned* __restrict__ ws_cnt,
    float* __restrict__ ws_part, unsigned* __restrict__ ws_pcnt, int mode)
{
    __shared__ int      lblt[SEG_ROWS_B];
    __shared__ unsigned cnts[C_CLS];

    const int tid  = threadIdx.x;
    const int lane = tid & 63;
    const int w    = tid >> 6;        // wave id 0..3 -> d-cols [w*32, w*32+32)
    const int qk   = lane >> 4;
    const int ln   = lane & 15;
    const int sb   = blockIdx.x;
    const int r0   = sb * SEG_ROWS_B;

    if (tid < C_CLS) cnts[tid] = 0u;
    __syncthreads();
    {
        const int lv = label[r0 + tid];   // 256 rows, 256 threads
        lblt[tid] = lv;
        atomicAdd(&cnts[lv], 1u);
    }
    __syncthreads();

    const int cbase = w * 32;
    f32x4 acc[4][2];                      // [c-tile][d-tile], 32 VGPR
    #pragma unroll
    for (int ct = 0; ct < 4; ++ct) {
        acc[ct][0] = (f32x4){0.f, 0.f, 0.f, 0.f};
        acc[ct][1] = (f32x4){0.f, 0.f, 0.f, 0.f};
    }

    for (int kk = 0; kk < SEG_KSTEPS; ++kk) {
        const int kr = kk * 32 + qk * 8;  // this lane's 8 k-rows
        const float* bp = f + (size_t)(r0 + kr) * D_FEAT + cbase + ln;
        float b0[8], b1[8];
        #pragma unroll
        for (int j = 0; j < 8; ++j) {
            b0[j] = bp[(size_t)j * D_FEAT];
            b1[j] = bp[(size_t)j * D_FEAT + 16];
        }
        int lb[8];
        #pragma unroll
        for (int j = 0; j < 8; ++j) lb[j] = lblt[kr + j];   // LDS broadcast
        bf16x8 bf0, bf1;
        #pragma unroll
        for (int j = 0; j < 8; ++j) { bf0[j] = f2bf(b0[j]); bf1[j] = f2bf(b1[j]); }
        #pragma unroll
        for (int ct = 0; ct < 4; ++ct) {
            const int cls = ct * 16 + ln;   // A-frag: m = ln (class), k = qk*8+j
            bf16x8 a;
            #pragma unroll
            for (int j = 0; j < 8; ++j)
                a[j] = (lb[j] == cls) ? (short)0x3F80 : (short)0;
            acc[ct][0] = __builtin_amdgcn_mfma_f32_16x16x32_bf16(a, bf0, acc[ct][0], 0, 0, 0);
            acc[ct][1] = __builtin_amdgcn_mfma_f32_16x16x32_bf16(a, bf1, acc[ct][1], 0, 0, 0);
        }
    }

    // D layout: m(class) = qk*4+u, n(d) = ln
    if (mode == 1) {
        float* dst = ws_part + (size_t)sb * SEG_ELEMS;
        #pragma unroll
        for (int ct = 0; ct < 4; ++ct)
            #pragma unroll
            for (int dt = 0; dt < 2; ++dt)
                #pragma unroll
                for (int u = 0; u < 4; ++u)
                    dst[(ct * 16 + qk * 4 + u) * D_FEAT + cbase + dt * 16 + ln] = acc[ct][dt][u];
        if (tid < C_CLS) ws_pcnt[sb * C_CLS + tid] = cnts[tid];
    } else {
        #pragma unroll
        for (int ct = 0; ct < 4; ++ct)
            for (int dt = 0; dt < 2; ++dt)
                for (int u = 0; u < 4; ++u)
                    unsafeAtomicAdd(&ws_seg[(ct * 16 + qk * 4 + u) * D_FEAT
                                            + cbase + dt * 16 + ln], acc[ct][dt][u]);
        if (tid < C_CLS) atomicAdd(&ws_cnt[tid], cnts[tid]);
    }
}

// v9c: merged reduce+finalize (MODE-1 path). 32 blocks x 256 threads; each
// thread owns one output element, sums all 1024 slices (coalesced 1KB runs),
// and writes out directly. No ws_seg/ws_cnt/ws_loss, no memset needed.
__global__ __launch_bounds__(256) void center_redfin(
    const float* __restrict__ ws_part, const unsigned* __restrict__ ws_pcnt,
    const float* __restrict__ ws_ploss, const float* __restrict__ centers,
    float* __restrict__ out)
{
    __shared__ float lred[4];
    __shared__ float cntf[2];
    const int tid = threadIdx.x;
    const int bid = blockIdx.x;
    const int i   = bid * 256 + tid;           // 0..8191
    const int wv  = tid >> 6, wl = tid & 63;

    // counts for this block's 2 classes: wave0 -> 2*bid, wave1 -> 2*bid+1
    if (wv < 2) {
        const int c = bid * 2 + wv;
        unsigned cs = 0u;
        for (int b = wl; b < SEG_BLOCKS; b += 64) cs += ws_pcnt[b * C_CLS + c];
        #pragma unroll
        for (int off = 32; off; off >>= 1) cs += __shfl_xor(cs, off);
        if (wl == 0) cntf[wv] = (float)cs;
    }

    // seg element i: sum over all 1024 slices
    float s = 0.f;
    #pragma unroll 8
    for (int b = 0; b < SEG_BLOCKS; ++b)
        s += ws_part[(size_t)b * SEG_ELEMS + i];

    // loss (block 0 only)
    if (bid == 0) {
        float ls = ws_ploss[tid] + ws_ploss[tid + 256]
                 + ws_ploss[tid + 512] + ws_ploss[tid + 768];
        #pragma unroll
        for (int off = 32; off; off >>= 1) ls += __shfl_xor(ls, off);
        if (wl == 0) lred[wv] = ls;
    }
    __syncthreads();
    if (bid == 0 && tid == 0)
        out[0] = (lred[0] + lred[1] + lred[2] + lred[3])
               / ((float)N_TOK * (float)D_FEAT);

    const float cnt   = cntf[tid >> 7];        // class = i>>7 = 2*bid + (tid>>7)
    const float denom = fmaxf(cnt, 1.f);
    out[1 + i] = (cnt * centers[i] - s) / denom;
}

// fallback finalize (mode 0)
__global__ void center_fin(const float* __restrict__ centers,
                           const float* __restrict__ ws_loss,
                           const unsigned* __restrict__ ws_cnt,
                           const float* __restrict__ ws_seg,
                           float* __restrict__ out)
{
    const int i = blockIdx.x * 256 + threadIdx.x;
    if (i == 0) out[0] = ws_loss[0] / ((float)N_TOK * (float)D_FEAT);
    if (i < SEG_ELEMS) {
        const int c = i >> 7;
        const unsigned cnt = ws_cnt[c];
        const float denom = (float)(cnt > 1u ? cnt : 1u);
        out[1 + i] = ((float)cnt * centers[i] - ws_seg[i]) / denom;
    }
}

extern "C" void kernel_launch(void* const* d_in, const int* in_sizes, int n_in,
                              void* d_out, int out_size, void* d_ws, size_t ws_size,
                              hipStream_t stream)
{
    const float* f       = (const float*)d_in[0];
    const int*   lbl     = (const int*)d_in[1];
    const float* centers = (const float*)d_in[2];
    float* out = (float*)d_out;

    float*    ws_loss  = (float*)d_ws;
    unsigned* ws_cnt   = (unsigned*)((char*)d_ws + 256);
    float*    ws_seg   = (float*)((char*)d_ws + 1024);
    char*     p        = (char*)d_ws + 1024 + SEG_ELEMS * sizeof(float);
    float*    ws_part  = (float*)p;                                   // 33.55 MB
    unsigned* ws_pcnt  = (unsigned*)(p + (size_t)SEG_BLOCKS * SEG_ELEMS * sizeof(float));
    float*    ws_ploss = (float*)(p + (size_t)SEG_BLOCKS * SEG_ELEMS * sizeof(float)
                                     + (size_t)SEG_BLOCKS * C_CLS * sizeof(unsigned));

    const size_t need = 1024 + SEG_ELEMS * sizeof(float)
                      + (size_t)SEG_BLOCKS * SEG_ELEMS * sizeof(float)
                      + (size_t)SEG_BLOCKS * C_CLS * sizeof(unsigned)
                      + (size_t)DIST_BLOCKS * sizeof(float);

    float* dist_out = out + 1 + SEG_ELEMS;
    if (ws_size >= need) {
        // no memset: MODE-1 never reads ws_loss/ws_cnt/ws_seg
        dist_main<<<DIST_BLOCKS, BLOCK_T, 0, stream>>>(f, lbl, centers, dist_out,
                                                       ws_loss, ws_ploss, 1);
        seg_main<<<SEG_BLOCKS, BLOCK_T, 0, stream>>>(f, lbl, ws_seg, ws_cnt,
                                                     ws_part, ws_pcnt, 1);
        center_redfin<<<32, 256, 0, stream>>>(ws_part, ws_pcnt, ws_ploss,
                                              centers, out);
    } else {
        hipMemsetAsync(d_ws, 0, 1024 + SEG_ELEMS * sizeof(float), stream);
        dist_main<<<DIST_BLOCKS, BLOCK_T, 0, stream>>>(f, lbl, centers, dist_out,
                                                       ws_loss, ws_ploss, 0);
        seg_main<<<SEG_BLOCKS, BLOCK_T, 0, stream>>>(f, lbl, ws_seg, ws_cnt,
                                                     ws_part, ws_pcnt, 0);
        center_fin<<<32, 256, 0, stream>>>(centers, ws_loss, ws_cnt, ws_seg, out);
    }
}